// Round 1
// baseline (1707.116 us; speedup 1.0000x reference)
//
#include <hip/hip_runtime.h>
#include <hip/hip_bf16.h>

#define BB 2
#define SS 1024
#define EE 1024
#define HH 8
#define DKK 128
#define HIDD 2048
#define VV 32000

typedef unsigned short u16;
typedef __attribute__((ext_vector_type(4))) float f32x4;
typedef __attribute__((ext_vector_type(8))) short s16x8;

__device__ __forceinline__ u16 f2b(float f) {
  union { float f; unsigned u; } v; v.f = f;
  unsigned r = v.u + 0x7fffu + ((v.u >> 16) & 1u);
  return (u16)(r >> 16);
}

// ---------------- weight convert + transpose: src [K][N] f32 -> dst [N][K] bf16
__global__ __launch_bounds__(256) void wconv_t(const float* __restrict__ src,
    u16* __restrict__ dst, int K, int N) {
  __shared__ float tile[32][33];
  size_t zo = (size_t)blockIdx.z * K * N;
  src += zo; dst += zo;
  int n0 = blockIdx.x * 32, k0 = blockIdx.y * 32;
  int tx = threadIdx.x & 31, ty = threadIdx.x >> 5;
#pragma unroll
  for (int i = 0; i < 32; i += 8)
    tile[ty + i][tx] = src[(size_t)(k0 + ty + i) * N + n0 + tx];
  __syncthreads();
#pragma unroll
  for (int i = 0; i < 32; i += 8)
    dst[(size_t)(n0 + ty + i) * K + k0 + tx] = f2b(tile[tx][ty + i]);
}

// ---------------- embedding + positional encoding
__global__ __launch_bounds__(256) void embed_k(const int* __restrict__ idx,
    const float* __restrict__ emb, const float* __restrict__ pos,
    float* __restrict__ of, u16* __restrict__ ob) {
  int row = blockIdx.x;
  int s = row & (SS - 1);
  int t = threadIdx.x;
  int id = idx[row];
  float4 v = ((const float4*)(emb + (size_t)id * EE))[t];
  float4 p = ((const float4*)(pos + (size_t)s * EE))[t];
  v.x += p.x; v.y += p.y; v.z += p.z; v.w += p.w;
  ((float4*)(of + (size_t)row * EE))[t] = v;
  ushort4 b4; b4.x = f2b(v.x); b4.y = f2b(v.y); b4.z = f2b(v.z); b4.w = f2b(v.w);
  ((ushort4*)(ob + (size_t)row * EE))[t] = b4;
}

// ---------------- reductions (256-thread blocks, 4 waves)
__device__ __forceinline__ float wsum(float v) {
#pragma unroll
  for (int o = 1; o < 64; o <<= 1) v += __shfl_xor(v, o, 64);
  return v;
}
__device__ __forceinline__ float wmax(float v) {
#pragma unroll
  for (int o = 1; o < 64; o <<= 1) v = fmaxf(v, __shfl_xor(v, o, 64));
  return v;
}
__device__ __forceinline__ float bsum(float v, float* sb) {
  v = wsum(v);
  __syncthreads();
  if ((threadIdx.x & 63) == 0) sb[threadIdx.x >> 6] = v;
  __syncthreads();
  return sb[0] + sb[1] + sb[2] + sb[3];
}
__device__ __forceinline__ float bmax(float v, float* sb) {
  v = wmax(v);
  __syncthreads();
  if ((threadIdx.x & 63) == 0) sb[threadIdx.x >> 6] = v;
  __syncthreads();
  return fmaxf(fmaxf(sb[0], sb[1]), fmaxf(sb[2], sb[3]));
}

// ---------------- LayerNorm (row = 1024), writes f32 + bf16
__global__ __launch_bounds__(256) void ln_k(const float* __restrict__ x,
    const float* __restrict__ g, const float* __restrict__ bta,
    float* __restrict__ of, u16* __restrict__ ob) {
  __shared__ float sb[4];
  int row = blockIdx.x, t = threadIdx.x;
  float4 v = ((const float4*)(x + (size_t)row * EE))[t];
  float mean = bsum(v.x + v.y + v.z + v.w, sb) * (1.0f / EE);
  float dx = v.x - mean, dy = v.y - mean, dz = v.z - mean, dw = v.w - mean;
  float var = bsum(dx * dx + dy * dy + dz * dz + dw * dw, sb) * (1.0f / EE);
  float rstd = rsqrtf(var + 1e-15f);
  float4 gg = ((const float4*)g)[t];
  float4 bb = ((const float4*)bta)[t];
  float4 o;
  o.x = gg.x * dx * rstd + bb.x;
  o.y = gg.y * dy * rstd + bb.y;
  o.z = gg.z * dz * rstd + bb.z;
  o.w = gg.w * dw * rstd + bb.w;
  ((float4*)(of + (size_t)row * EE))[t] = o;
  ushort4 b4; b4.x = f2b(o.x); b4.y = f2b(o.y); b4.z = f2b(o.z); b4.w = f2b(o.w);
  ((ushort4*)(ob + (size_t)row * EE))[t] = b4;
}

// ---------------- attention softmax: scores f32 [16*S][S] -> probs bf16, scale+mask here
__global__ __launch_bounds__(256) void smax_k(const float* __restrict__ sc,
    u16* __restrict__ pb, int causal) {
  __shared__ float sb[4];
  int row = blockIdx.x;
  int q = row & (SS - 1);
  int t = threadIdx.x;
  const float scale = 0.08838834764831845f;  // 1/sqrt(128)
  float4 v = ((const float4*)(sc + (size_t)row * SS))[t];
  int c0 = t * 4;
  bool k0 = !causal || (c0 + 0) <= q;
  bool k1 = !causal || (c0 + 1) <= q;
  bool k2 = !causal || (c0 + 2) <= q;
  bool k3 = !causal || (c0 + 3) <= q;
  float a0 = k0 ? v.x * scale : -1e30f;
  float a1 = k1 ? v.y * scale : -1e30f;
  float a2 = k2 ? v.z * scale : -1e30f;
  float a3 = k3 ? v.w * scale : -1e30f;
  float mx = bmax(fmaxf(fmaxf(a0, a1), fmaxf(a2, a3)), sb);
  float e0 = k0 ? __expf(a0 - mx) : 0.0f;
  float e1 = k1 ? __expf(a1 - mx) : 0.0f;
  float e2 = k2 ? __expf(a2 - mx) : 0.0f;
  float e3 = k3 ? __expf(a3 - mx) : 0.0f;
  float inv = 1.0f / bsum(e0 + e1 + e2 + e3, sb);
  ushort4 b4;
  b4.x = f2b(e0 * inv); b4.y = f2b(e1 * inv);
  b4.z = f2b(e2 * inv); b4.w = f2b(e3 * inv);
  ((ushort4*)(pb + (size_t)row * SS))[t] = b4;
}

// ---------------- final vocab softmax, in-place over d_out rows of 32000
__global__ __launch_bounds__(256) void vsmax_k(float* __restrict__ lg) {
  __shared__ float sb[4];
  int row = blockIdx.x, t = threadIdx.x;
  float* r = lg + (size_t)row * VV;
  float mx = -1e30f;
  for (int c = t; c < VV / 4; c += 256) {
    float4 v = ((const float4*)r)[c];
    mx = fmaxf(mx, fmaxf(fmaxf(v.x, v.y), fmaxf(v.z, v.w)));
  }
  float M = bmax(mx, sb);
  float s = 0.0f;
  for (int c = t; c < VV / 4; c += 256) {
    float4 v = ((const float4*)r)[c];
    s += __expf(v.x - M) + __expf(v.y - M) + __expf(v.z - M) + __expf(v.w - M);
  }
  float inv = 1.0f / bsum(s, sb);
  for (int c = t; c < VV / 4; c += 256) {
    float4 v = ((const float4*)r)[c];
    float4 o;
    o.x = __expf(v.x - M) * inv; o.y = __expf(v.y - M) * inv;
    o.z = __expf(v.z - M) * inv; o.w = __expf(v.w - M) * inv;
    ((float4*)r)[c] = o;
  }
}

// ---------------- bf16 MFMA GEMM, both operands K-contiguous ("NT"):
// C[M][N] = A[M][K] * B[N][K]^T (+bias[n]) (+res) ; writes f32 and/or bf16.
// Batched: z -> (bz=z/HH, hz=z%HH), element-stride offsets per operand.
// VT: bf16 write scattered to [b][h][d][s] layout (V projection).
template<bool BIAS, bool RELU, bool RES, bool WF32, bool WBF16, bool VT>
__global__ __launch_bounds__(256) void gemm_nt(
    const u16* __restrict__ A, const u16* __restrict__ Bm,
    const float* __restrict__ bias, const float* __restrict__ res,
    float* __restrict__ Cf, u16* __restrict__ Cb,
    int M, int N, int K, int lda, int ldb, int ldc,
    long long sAb, long long sAh, long long sBb, long long sBh,
    long long sCb, long long sCh) {
  (void)M; (void)N;
  int z = blockIdx.z;
  int bz = z / HH, hz = z % HH;
  A += bz * sAb + hz * sAh;
  Bm += bz * sBb + hz * sBh;
  size_t coff = (size_t)(bz * sCb + hz * sCh);

  __shared__ u16 As[128][40];
  __shared__ u16 Bs[128][40];

  int tid = threadIdx.x;
  int lane = tid & 63;
  int wave = tid >> 6;
  int wr = wave >> 1, wc = wave & 1;
  int m0 = blockIdx.y * 128, n0 = blockIdx.x * 128;
  int lrow = lane & 15;
  int lk8 = (lane >> 4) << 3;

  f32x4 acc[4][4] = {};

  for (int k0 = 0; k0 < K; k0 += 32) {
#pragma unroll
    for (int i = 0; i < 2; ++i) {
      int c = tid + i * 256;
      int r = c >> 2, c8 = (c & 3) << 3;
      uint4 va = *(const uint4*)(A + (size_t)(m0 + r) * lda + k0 + c8);
      *(uint4*)(&As[r][c8]) = va;
      uint4 vb = *(const uint4*)(Bm + (size_t)(n0 + r) * ldb + k0 + c8);
      *(uint4*)(&Bs[r][c8]) = vb;
    }
    __syncthreads();
    s16x8 af[4], bfr[4];
#pragma unroll
    for (int m = 0; m < 4; ++m)
      af[m] = *(const s16x8*)(&As[wr * 64 + m * 16 + lrow][lk8]);
#pragma unroll
    for (int n = 0; n < 4; ++n)
      bfr[n] = *(const s16x8*)(&Bs[wc * 64 + n * 16 + lrow][lk8]);
#pragma unroll
    for (int m = 0; m < 4; ++m)
#pragma unroll
      for (int n = 0; n < 4; ++n)
        acc[m][n] = __builtin_amdgcn_mfma_f32_16x16x32_bf16(af[m], bfr[n], acc[m][n], 0, 0, 0);
    __syncthreads();
  }

  int rbase = (lane >> 4) << 2;
  int cl = lane & 15;
#pragma unroll
  for (int m = 0; m < 4; ++m) {
#pragma unroll
    for (int n = 0; n < 4; ++n) {
#pragma unroll
      for (int r = 0; r < 4; ++r) {
        int row = m0 + wr * 64 + m * 16 + rbase + r;
        int col = n0 + wc * 64 + n * 16 + cl;
        float v = acc[m][n][r];
        if constexpr (BIAS) v += bias[col];
        if constexpr (RELU) v = fmaxf(v, 0.0f);
        if constexpr (RES) v += res[coff + (size_t)row * ldc + col];
        if constexpr (WF32) Cf[coff + (size_t)row * ldc + col] = v;
        if constexpr (WBF16) {
          if constexpr (VT) {
            int bb = row >> 10, sx = row & (SS - 1);
            int hh = col >> 7, dd = col & (DKK - 1);
            Cb[(((size_t)(bb * HH + hh) * DKK + dd) << 10) + sx] = f2b(v);
          } else {
            Cb[coff + (size_t)row * ldc + col] = f2b(v);
          }
        }
      }
    }
  }
}

extern "C" void kernel_launch(void* const* d_in, const int* in_sizes, int n_in,
                              void* d_out, int out_size, void* d_ws, size_t ws_size,
                              hipStream_t stream) {
  (void)in_sizes; (void)n_in; (void)out_size; (void)ws_size;
  const int* src = (const int*)d_in[0];
  const int* trg = (const int*)d_in[1];
  const float* embe = (const float*)d_in[2];
  const float* embd = (const float*)d_in[3];
  const float* pos = (const float*)d_in[4];
  const float* mha_w = (const float*)d_in[5];
  const float* mha_b = (const float*)d_in[6];
  const float* fw1 = (const float*)d_in[7];
  const float* fb1 = (const float*)d_in[8];
  const float* fw2 = (const float*)d_in[9];
  const float* fb2 = (const float*)d_in[10];
  const float* ng = (const float*)d_in[11];
  const float* nb = (const float*)d_in[12];
  const float* ww = (const float*)d_in[13];
  const float* wb = (const float*)d_in[14];
  float* out = (float*)d_out;

  char* ws = (char*)d_ws;
  size_t off = 0;
  auto alloc = [&](size_t bytes) -> void* {
    void* p = ws + off;
    off += (bytes + 255) & ~(size_t)255;
    return p;
  };

  u16* wt_mha = (u16*)alloc((size_t)12 * EE * EE * 2);
  u16* wt_f1 = (u16*)alloc((size_t)2 * EE * HIDD * 2);
  u16* wt_f2 = (u16*)alloc((size_t)2 * HIDD * EE * 2);
  u16* wt_o = (u16*)alloc((size_t)VV * EE * 2);
  float* f0 = (float*)alloc((size_t)BB * SS * EE * 4);
  float* f1 = (float*)alloc((size_t)BB * SS * EE * 4);
  float* f2 = (float*)alloc((size_t)BB * SS * EE * 4);
  float* f3 = (float*)alloc((size_t)BB * SS * EE * 4);
  u16* be = (u16*)alloc((size_t)BB * SS * EE * 2);
  u16* bd = (u16*)alloc((size_t)BB * SS * EE * 2);
  u16* qb = (u16*)alloc((size_t)BB * SS * EE * 2);
  u16* kb = (u16*)alloc((size_t)BB * SS * EE * 2);
  u16* vt = (u16*)alloc((size_t)BB * HH * DKK * SS * 2);
  u16* ao = (u16*)alloc((size_t)BB * SS * EE * 2);
  u16* hb = (u16*)alloc((size_t)BB * SS * HIDD * 2);
  u16* pb = (u16*)alloc((size_t)BB * HH * SS * SS * 2);
  float* sc = (float*)alloc((size_t)BB * HH * SS * SS * 4);

  // weights -> bf16 transposed [N][K]
  wconv_t<<<dim3(EE / 32, EE / 32, 12), 256, 0, stream>>>(mha_w, wt_mha, EE, EE);
  wconv_t<<<dim3(HIDD / 32, EE / 32, 2), 256, 0, stream>>>(fw1, wt_f1, EE, HIDD);
  wconv_t<<<dim3(EE / 32, HIDD / 32, 2), 256, 0, stream>>>(fw2, wt_f2, HIDD, EE);
  wconv_t<<<dim3(VV / 32, EE / 32, 1), 256, 0, stream>>>(ww, wt_o, EE, VV);

  const int M = BB * SS;

  auto attn_block = [&](const u16* xq, const u16* xkv, const float* resid,
                        int blk, int causal, float* outf) {
    const u16* wq = wt_mha + (size_t)(blk * 4 + 0) * EE * EE;
    const u16* wk = wt_mha + (size_t)(blk * 4 + 1) * EE * EE;
    const u16* wv = wt_mha + (size_t)(blk * 4 + 2) * EE * EE;
    const u16* wo = wt_mha + (size_t)(blk * 4 + 3) * EE * EE;
    const float* bq = mha_b + (blk * 4 + 0) * EE;
    const float* bk = mha_b + (blk * 4 + 1) * EE;
    const float* bv = mha_b + (blk * 4 + 2) * EE;
    const float* bo = mha_b + (blk * 4 + 3) * EE;
    gemm_nt<true, false, false, false, true, false><<<dim3(8, 16, 1), 256, 0, stream>>>(
        xq, wq, bq, nullptr, nullptr, qb, M, EE, EE, EE, EE, EE, 0, 0, 0, 0, 0, 0);
    gemm_nt<true, false, false, false, true, false><<<dim3(8, 16, 1), 256, 0, stream>>>(
        xkv, wk, bk, nullptr, nullptr, kb, M, EE, EE, EE, EE, EE, 0, 0, 0, 0, 0, 0);
    gemm_nt<true, false, false, false, true, true><<<dim3(8, 16, 1), 256, 0, stream>>>(
        xkv, wv, bv, nullptr, nullptr, vt, M, EE, EE, EE, EE, EE, 0, 0, 0, 0, 0, 0);
    // scores: per (b,h): Q[S][128] x K[S][128]^T -> sc[S][S]
    gemm_nt<false, false, false, true, false, false><<<dim3(8, 8, 16), 256, 0, stream>>>(
        qb, kb, nullptr, nullptr, sc, nullptr, SS, SS, DKK, EE, EE, SS,
        (long long)SS * EE, DKK, (long long)SS * EE, DKK,
        (long long)HH * SS * SS, (long long)SS * SS);
    smax_k<<<dim3(BB * HH * SS), 256, 0, stream>>>(sc, pb, causal);
    // PV: P[S][S] x Vt[128][S]^T -> ao[b][s][h*128+d]
    gemm_nt<false, false, false, false, true, false><<<dim3(1, 8, 16), 256, 0, stream>>>(
        pb, vt, nullptr, nullptr, nullptr, ao, SS, DKK, SS, SS, SS, EE,
        (long long)HH * SS * SS, (long long)SS * SS,
        (long long)HH * DKK * SS, (long long)DKK * SS,
        (long long)SS * EE, DKK);
    gemm_nt<true, false, true, true, false, false><<<dim3(8, 16, 1), 256, 0, stream>>>(
        ao, wo, bo, resid, outf, nullptr, M, EE, EE, EE, EE, EE, 0, 0, 0, 0, 0, 0);
  };

  auto ffn_block = [&](const u16* x, const float* resid, int blk, float* outf) {
    gemm_nt<true, true, false, false, true, false><<<dim3(16, 16, 1), 256, 0, stream>>>(
        x, wt_f1 + (size_t)blk * EE * HIDD, fb1 + blk * HIDD, nullptr, nullptr, hb,
        M, HIDD, EE, EE, EE, HIDD, 0, 0, 0, 0, 0, 0);
    gemm_nt<true, false, true, true, false, false><<<dim3(8, 16, 1), 256, 0, stream>>>(
        hb, wt_f2 + (size_t)blk * HIDD * EE, fb2 + blk * EE, resid, outf, nullptr,
        M, EE, HIDD, HIDD, HIDD, EE, 0, 0, 0, 0, 0, 0);
  };

  // ---- encoder
  embed_k<<<dim3(M), 256, 0, stream>>>(src, embe, pos, f0, be);
  attn_block(be, be, f0, 0, 0, f3);
  ln_k<<<dim3(M), 256, 0, stream>>>(f3, ng + 0 * EE, nb + 0 * EE, f0, be);
  ffn_block(be, f0, 0, f3);
  ln_k<<<dim3(M), 256, 0, stream>>>(f3, ng + 1 * EE, nb + 1 * EE, f1, be);
  // ---- decoder
  embed_k<<<dim3(M), 256, 0, stream>>>(trg, embd, pos, f2, bd);
  attn_block(bd, bd, f2, 1, 1, f3);
  ln_k<<<dim3(M), 256, 0, stream>>>(f3, ng + 2 * EE, nb + 2 * EE, f2, bd);
  attn_block(bd, be, f2, 2, 0, f3);
  ln_k<<<dim3(M), 256, 0, stream>>>(f3, ng + 3 * EE, nb + 3 * EE, f2, bd);
  ffn_block(bd, f2, 1, f3);
  ln_k<<<dim3(M), 256, 0, stream>>>(f3, ng + 4 * EE, nb + 4 * EE, f2, bd);
  // ---- output projection + softmax
  gemm_nt<true, false, false, true, false, false><<<dim3(VV / 128, 16, 1), 256, 0, stream>>>(
      bd, wt_o, wb, nullptr, out, nullptr, M, VV, EE, EE, EE, VV, 0, 0, 0, 0, 0, 0);
  vsmax_k<<<dim3(M), 256, 0, stream>>>(out);
}

// Round 6
// 1527.563 us; speedup vs baseline: 1.1175x; 1.1175x over previous
//
#include <hip/hip_runtime.h>
#include <hip/hip_bf16.h>

#define BB 2
#define SS 1024
#define EE 1024
#define HH 8
#define DKK 128
#define HIDD 2048
#define VV 32000

typedef unsigned short u16;
typedef __attribute__((ext_vector_type(4))) float f32x4;
typedef __attribute__((ext_vector_type(8))) short s16x8;

__device__ __forceinline__ u16 f2b(float f) {
  union { float f; unsigned u; } v; v.f = f;
  unsigned r = v.u + 0x7fffu + ((v.u >> 16) & 1u);
  return (u16)(r >> 16);
}

typedef __attribute__((address_space(1))) const unsigned gu32;
typedef __attribute__((address_space(3))) unsigned lu32;
__device__ __forceinline__ void gld16(const u16* g, u16* l) {
  __builtin_amdgcn_global_load_lds((gu32*)g, (lu32*)l, 16, 0, 0);
}

// ---------------- weight convert + transpose: src [K][N] f32 -> dst [N][K] bf16
__global__ __launch_bounds__(256) void wconv_t(const float* __restrict__ src,
    u16* __restrict__ dst, int K, int N) {
  __shared__ float tile[32][33];
  size_t zo = (size_t)blockIdx.z * K * N;
  src += zo; dst += zo;
  int n0 = blockIdx.x * 32, k0 = blockIdx.y * 32;
  int tx = threadIdx.x & 31, ty = threadIdx.x >> 5;
#pragma unroll
  for (int i = 0; i < 32; i += 8)
    tile[ty + i][tx] = src[(size_t)(k0 + ty + i) * N + n0 + tx];
  __syncthreads();
#pragma unroll
  for (int i = 0; i < 32; i += 8)
    dst[(size_t)(n0 + ty + i) * K + k0 + tx] = f2b(tile[tx][ty + i]);
}

// ---------------- embedding + positional encoding
__global__ __launch_bounds__(256) void embed_k(const int* __restrict__ idx,
    const float* __restrict__ emb, const float* __restrict__ pos,
    float* __restrict__ of, u16* __restrict__ ob) {
  int row = blockIdx.x;
  int s = row & (SS - 1);
  int t = threadIdx.x;
  int id = idx[row];
  float4 v = ((const float4*)(emb + (size_t)id * EE))[t];
  float4 p = ((const float4*)(pos + (size_t)s * EE))[t];
  v.x += p.x; v.y += p.y; v.z += p.z; v.w += p.w;
  ((float4*)(of + (size_t)row * EE))[t] = v;
  ushort4 b4; b4.x = f2b(v.x); b4.y = f2b(v.y); b4.z = f2b(v.z); b4.w = f2b(v.w);
  ((ushort4*)(ob + (size_t)row * EE))[t] = b4;
}

// ---------------- reductions (256-thread blocks, 4 waves)
__device__ __forceinline__ float wsum(float v) {
#pragma unroll
  for (int o = 1; o < 64; o <<= 1) v += __shfl_xor(v, o, 64);
  return v;
}
__device__ __forceinline__ float wmax(float v) {
#pragma unroll
  for (int o = 1; o < 64; o <<= 1) v = fmaxf(v, __shfl_xor(v, o, 64));
  return v;
}
__device__ __forceinline__ float bsum(float v, float* sb) {
  v = wsum(v);
  __syncthreads();
  if ((threadIdx.x & 63) == 0) sb[threadIdx.x >> 6] = v;
  __syncthreads();
  return sb[0] + sb[1] + sb[2] + sb[3];
}
__device__ __forceinline__ float bmax(float v, float* sb) {
  v = wmax(v);
  __syncthreads();
  if ((threadIdx.x & 63) == 0) sb[threadIdx.x >> 6] = v;
  __syncthreads();
  return fmaxf(fmaxf(sb[0], sb[1]), fmaxf(sb[2], sb[3]));
}

// ---------------- LayerNorm (row = 1024), writes f32 + bf16
__global__ __launch_bounds__(256) void ln_k(const float* __restrict__ x,
    const float* __restrict__ g, const float* __restrict__ bta,
    float* __restrict__ of, u16* __restrict__ ob) {
  __shared__ float sb[4];
  int row = blockIdx.x, t = threadIdx.x;
  float4 v = ((const float4*)(x + (size_t)row * EE))[t];
  float mean = bsum(v.x + v.y + v.z + v.w, sb) * (1.0f / EE);
  float dx = v.x - mean, dy = v.y - mean, dz = v.z - mean, dw = v.w - mean;
  float var = bsum(dx * dx + dy * dy + dz * dz + dw * dw, sb) * (1.0f / EE);
  float rstd = rsqrtf(var + 1e-15f);
  float4 gg = ((const float4*)g)[t];
  float4 bb = ((const float4*)bta)[t];
  float4 o;
  o.x = gg.x * dx * rstd + bb.x;
  o.y = gg.y * dy * rstd + bb.y;
  o.z = gg.z * dz * rstd + bb.z;
  o.w = gg.w * dw * rstd + bb.w;
  ((float4*)(of + (size_t)row * EE))[t] = o;
  ushort4 b4; b4.x = f2b(o.x); b4.y = f2b(o.y); b4.z = f2b(o.z); b4.w = f2b(o.w);
  ((ushort4*)(ob + (size_t)row * EE))[t] = b4;
}

// ---------------- attention softmax: scores f32 [16*S][S] -> probs bf16
__global__ __launch_bounds__(256) void smax_k(const float* __restrict__ sc,
    u16* __restrict__ pb, int causal) {
  __shared__ float sb[4];
  int row = blockIdx.x;
  int q = row & (SS - 1);
  int t = threadIdx.x;
  const float scale = 0.08838834764831845f;  // 1/sqrt(128)
  float4 v = ((const float4*)(sc + (size_t)row * SS))[t];
  int c0 = t * 4;
  bool k0 = !causal || (c0 + 0) <= q;
  bool k1 = !causal || (c0 + 1) <= q;
  bool k2 = !causal || (c0 + 2) <= q;
  bool k3 = !causal || (c0 + 3) <= q;
  float a0 = k0 ? v.x * scale : -1e30f;
  float a1 = k1 ? v.y * scale : -1e30f;
  float a2 = k2 ? v.z * scale : -1e30f;
  float a3 = k3 ? v.w * scale : -1e30f;
  float mx = bmax(fmaxf(fmaxf(a0, a1), fmaxf(a2, a3)), sb);
  float e0 = k0 ? __expf(a0 - mx) : 0.0f;
  float e1 = k1 ? __expf(a1 - mx) : 0.0f;
  float e2 = k2 ? __expf(a2 - mx) : 0.0f;
  float e3 = k3 ? __expf(a3 - mx) : 0.0f;
  float inv = 1.0f / bsum(e0 + e1 + e2 + e3, sb);
  ushort4 b4;
  b4.x = f2b(e0 * inv); b4.y = f2b(e1 * inv);
  b4.z = f2b(e2 * inv); b4.w = f2b(e3 * inv);
  ((ushort4*)(pb + (size_t)row * SS))[t] = b4;
}

// ---------------- final: probs = exp(logit) / rowsum  (sum was built in GEMM epilogue)
__global__ __launch_bounds__(256) void psmax_k(float* __restrict__ lg,
    const float* __restrict__ rs) {
  int row = blockIdx.x, t = threadIdx.x;
  float inv = 1.0f / rs[row];
  float4* p = (float4*)(lg + (size_t)row * VV);
  for (int c = t; c < VV / 4; c += 256) {
    float4 v = p[c];
    v.x = __expf(v.x) * inv; v.y = __expf(v.y) * inv;
    v.z = __expf(v.z) * inv; v.w = __expf(v.w) * inv;
    p[c] = v;
  }
}

// ---------------- bf16 MFMA GEMM (m97 structure: global_load_lds width-16),
// C[M][N] = A[M][K] * B[N][K]^T. Tiles 128x128, BK=32, 4 waves.
// SWZ: XCD-chunked bijective remap + M-fastest decomposition (B-tile L2 reuse).
// QKV: epilogue splits columns (lcol=col+qkvoff) into q / k / v-transposed dests.
// SMEXP: accumulate sum(exp(v)) per row via cross-lane reduce + atomicAdd.
template<bool BIAS, bool RELU, bool RES, bool WF32, bool WBF16, bool QKV, bool SMEXP, bool SWZ>
__global__ __launch_bounds__(256) void gemm_nt(
    const u16* __restrict__ A, const u16* __restrict__ Bm,
    const float* __restrict__ bias, const float* __restrict__ res,
    float* __restrict__ Cf, u16* __restrict__ Cb,
    u16* __restrict__ Cb2, u16* __restrict__ Cb3,
    float* __restrict__ rowsum, int qkvoff,
    int K, int lda, int ldb, int ldc,
    long long sAb, long long sAh, long long sBb, long long sBh,
    long long sCb, long long sCh) {
  int z = blockIdx.z;
  int bz = z / HH, hz = z % HH;
  A += bz * sAb + hz * sAh;
  Bm += bz * sBb + hz * sBh;
  size_t coff = (size_t)(bz * sCb + hz * sCh);

  __shared__ __align__(16) u16 As[128 * 32];
  __shared__ __align__(16) u16 Bs[128 * 32];

  int tid = threadIdx.x;
  int lane = tid & 63;
  int wave = tid >> 6;
  int wr = wave >> 1, wc = wave & 1;

  int mi, ni;
  if constexpr (SWZ) {
    int nwg = gridDim.x * gridDim.y;
    int flat = blockIdx.x + gridDim.x * blockIdx.y;
    int q8 = nwg >> 3, r8 = nwg & 7;
    int xcd = flat & 7, sub = flat >> 3;
    int wg = (xcd < r8 ? xcd * (q8 + 1) : r8 * (q8 + 1) + (xcd - r8) * q8) + sub;
    mi = wg % gridDim.y;
    ni = wg / gridDim.y;
  } else {
    mi = blockIdx.y; ni = blockIdx.x;
  }
  int m0 = mi * 128, n0 = ni * 128;

  int lrow = lane & 15;
  int lk8 = (lane >> 4) << 3;

  f32x4 acc[4][4] = {};

  for (int k0 = 0; k0 < K; k0 += 32) {
#pragma unroll
    for (int i = 0; i < 2; ++i) {
      int c = tid + i * 256;
      int r = c >> 2, c8 = (c & 3) << 3;
      gld16(A + (size_t)(m0 + r) * lda + k0 + c8, &As[r * 32 + c8]);
      gld16(Bm + (size_t)(n0 + r) * ldb + k0 + c8, &Bs[r * 32 + c8]);
    }
    __syncthreads();
    s16x8 af[4], bfr[4];
#pragma unroll
    for (int m = 0; m < 4; ++m)
      af[m] = *(const s16x8*)(&As[(wr * 64 + m * 16 + lrow) * 32 + lk8]);
#pragma unroll
    for (int n = 0; n < 4; ++n)
      bfr[n] = *(const s16x8*)(&Bs[(wc * 64 + n * 16 + lrow) * 32 + lk8]);
#pragma unroll
    for (int m = 0; m < 4; ++m)
#pragma unroll
      for (int n = 0; n < 4; ++n)
        acc[m][n] = __builtin_amdgcn_mfma_f32_16x16x32_bf16(af[m], bfr[n], acc[m][n], 0, 0, 0);
    __syncthreads();
  }

  int rbase = (lane >> 4) << 2;
  int cl = lane & 15;
  float esum[4][4] = {};  // [m][r]
#pragma unroll
  for (int m = 0; m < 4; ++m) {
#pragma unroll
    for (int n = 0; n < 4; ++n) {
#pragma unroll
      for (int r = 0; r < 4; ++r) {
        int row = m0 + wr * 64 + m * 16 + rbase + r;
        int col = n0 + wc * 64 + n * 16 + cl;
        float v = acc[m][n][r];
        if constexpr (BIAS) v += bias[col];
        if constexpr (RELU) v = fmaxf(v, 0.0f);
        if constexpr (RES) v += res[coff + (size_t)row * ldc + col];
        if constexpr (WF32) Cf[coff + (size_t)row * ldc + col] = v;
        if constexpr (SMEXP) esum[m][r] += __expf(v);
        if constexpr (WBF16) Cb[coff + (size_t)row * ldc + col] = f2b(v);
        if constexpr (QKV) {
          int lcol = col + qkvoff;
          int seg = lcol >> 10;  // block-uniform (n0 is 128-aligned)
          u16 bv = f2b(v);
          if (seg == 0) {
            Cb[(size_t)row * EE + (lcol & 1023)] = bv;
          } else if (seg == 1) {
            Cb2[(size_t)row * EE + (lcol & 1023)] = bv;
          } else {
            int bb = row >> 10, sx = row & (SS - 1);
            int h = (lcol >> 7) & 7, dd = lcol & (DKK - 1);
            Cb3[(((size_t)(bb * HH + h) * DKK + dd) << 10) + sx] = bv;
          }
        }
      }
    }
  }
  if constexpr (SMEXP) {
#pragma unroll
    for (int m = 0; m < 4; ++m)
#pragma unroll
      for (int r = 0; r < 4; ++r) {
        float p = esum[m][r];
        p += __shfl_xor(p, 1, 64);
        p += __shfl_xor(p, 2, 64);
        p += __shfl_xor(p, 4, 64);
        p += __shfl_xor(p, 8, 64);
        if (cl == 0)
          atomicAdd(&rowsum[m0 + wr * 64 + m * 16 + rbase + r], p);
      }
  }
}

extern "C" void kernel_launch(void* const* d_in, const int* in_sizes, int n_in,
                              void* d_out, int out_size, void* d_ws, size_t ws_size,
                              hipStream_t stream) {
  (void)in_sizes; (void)n_in; (void)out_size; (void)ws_size;
  const int* src = (const int*)d_in[0];
  const int* trg = (const int*)d_in[1];
  const float* embe = (const float*)d_in[2];
  const float* embd = (const float*)d_in[3];
  const float* pos = (const float*)d_in[4];
  const float* mha_w = (const float*)d_in[5];
  const float* mha_b = (const float*)d_in[6];
  const float* fw1 = (const float*)d_in[7];
  const float* fb1 = (const float*)d_in[8];
  const float* fw2 = (const float*)d_in[9];
  const float* fb2 = (const float*)d_in[10];
  const float* ng = (const float*)d_in[11];
  const float* nb = (const float*)d_in[12];
  const float* ww = (const float*)d_in[13];
  const float* wb = (const float*)d_in[14];
  float* out = (float*)d_out;

  char* ws = (char*)d_ws;
  size_t off = 0;
  auto alloc = [&](size_t bytes) -> void* {
    void* p = ws + off;
    off += (bytes + 255) & ~(size_t)255;
    return p;
  };

  u16* wt_mha = (u16*)alloc((size_t)12 * EE * EE * 2);
  u16* wt_f1 = (u16*)alloc((size_t)2 * EE * HIDD * 2);
  u16* wt_f2 = (u16*)alloc((size_t)2 * HIDD * EE * 2);
  u16* wt_o = (u16*)alloc((size_t)VV * EE * 2);
  float* f0 = (float*)alloc((size_t)BB * SS * EE * 4);
  float* f1 = (float*)alloc((size_t)BB * SS * EE * 4);
  float* f2 = (float*)alloc((size_t)BB * SS * EE * 4);
  float* f3 = (float*)alloc((size_t)BB * SS * EE * 4);
  u16* be = (u16*)alloc((size_t)BB * SS * EE * 2);
  u16* bd = (u16*)alloc((size_t)BB * SS * EE * 2);
  u16* qb = (u16*)alloc((size_t)BB * SS * EE * 2);
  u16* kb = (u16*)alloc((size_t)BB * SS * EE * 2);
  u16* vt = (u16*)alloc((size_t)BB * HH * DKK * SS * 2);
  u16* ao = (u16*)alloc((size_t)BB * SS * EE * 2);
  u16* hb = (u16*)alloc((size_t)BB * SS * HIDD * 2);
  u16* pb = (u16*)alloc((size_t)BB * HH * SS * SS * 2);
  float* sc = (float*)alloc((size_t)BB * HH * SS * SS * 4);
  float* rsum = (float*)alloc((size_t)BB * SS * 4);

  // weights -> bf16 transposed [N][K]
  wconv_t<<<dim3(EE / 32, EE / 32, 12), 256, 0, stream>>>(mha_w, wt_mha, EE, EE);
  wconv_t<<<dim3(HIDD / 32, EE / 32, 2), 256, 0, stream>>>(fw1, wt_f1, EE, HIDD);
  wconv_t<<<dim3(EE / 32, HIDD / 32, 2), 256, 0, stream>>>(fw2, wt_f2, HIDD, EE);
  wconv_t<<<dim3(VV / 32, EE / 32, 1), 256, 0, stream>>>(ww, wt_o, EE, VV);

  const int M = BB * SS;
  const long long Z0 = 0;

  auto attn_block = [&](const u16* xq, const u16* xkv, const float* resid,
                        int blk, int causal, float* outf) {
    const u16* wq = wt_mha + (size_t)(blk * 4 + 0) * EE * EE;
    const u16* wk = wt_mha + (size_t)(blk * 4 + 1) * EE * EE;
    const u16* wo = wt_mha + (size_t)(blk * 4 + 3) * EE * EE;
    const float* bq = mha_b + (blk * 4 + 0) * EE;
    const float* bk = mha_b + (blk * 4 + 1) * EE;
    const float* bo = mha_b + (blk * 4 + 3) * EE;
    if (xq == xkv) {
      // fused QKV: B = [wq;wk;wv] contiguous [3E][E]
      gemm_nt<true, false, false, false, false, true, false, true>
          <<<dim3(24, 16, 1), 256, 0, stream>>>(
          xq, wq, bq, nullptr, nullptr, qb, kb, vt, nullptr, 0,
          EE, EE, EE, 0, Z0, Z0, Z0, Z0, Z0, Z0);
    } else {
      gemm_nt<true, false, false, false, true, false, false, true>
          <<<dim3(8, 16, 1), 256, 0, stream>>>(
          xq, wq, bq, nullptr, nullptr, qb, nullptr, nullptr, nullptr, 0,
          EE, EE, EE, EE, Z0, Z0, Z0, Z0, Z0, Z0);
      // fused KV: B = [wk;wv] contiguous [2E][E]
      gemm_nt<true, false, false, false, false, true, false, true>
          <<<dim3(16, 16, 1), 256, 0, stream>>>(
          xkv, wk, bk, nullptr, nullptr, qb, kb, vt, nullptr, 1024,
          EE, EE, EE, 0, Z0, Z0, Z0, Z0, Z0, Z0);
    }
    // scores: per (b,h): Q[S][128] x K[S][128]^T -> sc[S][S]
    gemm_nt<false, false, false, true, false, false, false, false>
        <<<dim3(8, 8, 16), 256, 0, stream>>>(
        qb, kb, nullptr, nullptr, sc, nullptr, nullptr, nullptr, nullptr, 0,
        DKK, EE, EE, SS,
        (long long)SS * EE, DKK, (long long)SS * EE, DKK,
        (long long)HH * SS * SS, (long long)SS * SS);
    smax_k<<<dim3(BB * HH * SS), 256, 0, stream>>>(sc, pb, causal);
    // PV: P[S][S] x Vt[128][S]^T -> ao[b][s][h*128+d]
    gemm_nt<false, false, false, false, true, false, false, false>
        <<<dim3(1, 8, 16), 256, 0, stream>>>(
        pb, vt, nullptr, nullptr, nullptr, ao, nullptr, nullptr, nullptr, 0,
        SS, SS, SS, EE,
        (long long)HH * SS * SS, (long long)SS * SS,
        (long long)HH * DKK * SS, (long long)DKK * SS,
        (long long)SS * EE, DKK);
    gemm_nt<true, false, true, true, false, false, false, true>
        <<<dim3(8, 16, 1), 256, 0, stream>>>(
        ao, wo, bo, resid, outf, nullptr, nullptr, nullptr, nullptr, 0,
        EE, EE, EE, EE, Z0, Z0, Z0, Z0, Z0, Z0);
  };

  auto ffn_block = [&](const u16* x, const float* resid, int blk, float* outf) {
    gemm_nt<true, true, false, false, true, false, false, true>
        <<<dim3(16, 16, 1), 256, 0, stream>>>(
        x, wt_f1 + (size_t)blk * EE * HIDD, fb1 + blk * HIDD, nullptr, nullptr, hb,
        nullptr, nullptr, nullptr, 0,
        EE, EE, EE, HIDD, Z0, Z0, Z0, Z0, Z0, Z0);
    gemm_nt<true, false, true, true, false, false, false, true>
        <<<dim3(8, 16, 1), 256, 0, stream>>>(
        hb, wt_f2 + (size_t)blk * HIDD * EE, fb2 + blk * EE, resid, outf, nullptr,
        nullptr, nullptr, nullptr, 0,
        HIDD, HIDD, HIDD, EE, Z0, Z0, Z0, Z0, Z0, Z0);
  };

  // ---- encoder
  embed_k<<<dim3(M), 256, 0, stream>>>(src, embe, pos, f0, be);
  attn_block(be, be, f0, 0, 0, f3);
  ln_k<<<dim3(M), 256, 0, stream>>>(f3, ng + 0 * EE, nb + 0 * EE, f0, be);
  ffn_block(be, f0, 0, f3);
  ln_k<<<dim3(M), 256, 0, stream>>>(f3, ng + 1 * EE, nb + 1 * EE, f1, be);
  // ---- decoder
  embed_k<<<dim3(M), 256, 0, stream>>>(trg, embd, pos, f2, bd);
  attn_block(bd, bd, f2, 1, 1, f3);
  ln_k<<<dim3(M), 256, 0, stream>>>(f3, ng + 2 * EE, nb + 2 * EE, f2, bd);
  attn_block(bd, be, f2, 2, 0, f3);
  ln_k<<<dim3(M), 256, 0, stream>>>(f3, ng + 3 * EE, nb + 3 * EE, f2, bd);
  ffn_block(bd, f2, 1, f3);
  ln_k<<<dim3(M), 256, 0, stream>>>(f3, ng + 4 * EE, nb + 4 * EE, f2, bd);
  // ---- output projection (+ fused exp-rowsum) + prob normalize
  hipMemsetAsync(rsum, 0, (size_t)M * 4, stream);
  gemm_nt<true, false, false, true, false, false, true, true>
      <<<dim3(VV / 128, 16, 1), 256, 0, stream>>>(
      bd, wt_o, wb, nullptr, out, nullptr, nullptr, nullptr, rsum, 0,
      EE, EE, EE, VV, Z0, Z0, Z0, Z0, Z0, Z0);
  psmax_k<<<dim3(M), 256, 0, stream>>>(out, rsum);
}